// Round 1
// baseline (448.827 us; speedup 1.0000x reference)
//
#include <hip/hip_runtime.h>
#include <math.h>

#define NFFT   2048
#define HALFN  1024
#define K1     1025
#define KPAD   36
#define MTOT   1097   // K1 + 2*KPAD
#define NFRAMES 1001
#define TLEN   120000
#define BATCH  8
#define FPER   120

__device__ __forceinline__ float blockReduceSum(float v, float* s_red, int tid) {
#pragma unroll
    for (int off = 32; off > 0; off >>= 1) v += __shfl_down(v, off, 64);
    __syncthreads();                 // protect s_red from previous use
    if ((tid & 63) == 0) s_red[tid >> 6] = v;
    __syncthreads();
    return s_red[0] + s_red[1] + s_red[2] + s_red[3];
}

// In-place radix-2 DIT complex FFT, input must be loaded in bit-reversed order.
// Twiddles: twc[j]=cos(-2*pi*j/2048), tws[j]=sin(-2*pi*j/2048).
__device__ __forceinline__ void fft2048(float* re, float* im,
                                        const float* twc, const float* tws,
                                        int tid) {
    for (int s = 1; s <= 11; ++s) {
        int half = 1 << (s - 1);
#pragma unroll
        for (int q = 0; q < 4; ++q) {
            int t   = tid + (q << 8);
            int pos = t & (half - 1);
            int i0  = ((t >> (s - 1)) << s) + pos;
            int i1  = i0 + half;
            int twi = pos << (11 - s);
            float wr = twc[twi], wi = tws[twi];
            float xr = re[i1], xi = im[i1];
            float tr = wr * xr - wi * xi;
            float ti = wr * xi + wi * xr;
            float ur = re[i0], ui = im[i0];
            re[i0] = ur + tr; im[i0] = ui + ti;
            re[i1] = ur - tr; im[i1] = ui - ti;
        }
        __syncthreads();
    }
}

__global__ __launch_bounds__(256)
void cheaptrick_kernel(const float* __restrict__ x,
                       const float* __restrict__ f0in,
                       float* __restrict__ out) {
    __shared__ float s_re[NFFT];
    __shared__ float s_im[NFFT];
    __shared__ float s_twc[HALFN];
    __shared__ float s_tws[HALFN];
    __shared__ float s_P[K1];
    __shared__ float s_C[MTOT];
    __shared__ float s_scan[256];
    __shared__ float s_red[8];

    const int tid = threadIdx.x;
    const int n   = blockIdx.x;   // frame index
    const int b   = blockIdx.y;   // batch index

    // ---- twiddle table (once per block) ----
    for (int j = tid; j < HALFN; j += 256) {
        float ang = -6.283185307179586f * (float)j * (1.0f / 2048.0f);
        float sn, cs;
        sincosf(ang, &sn, &cs);
        s_twc[j] = cs; s_tws[j] = sn;
    }

    float f0 = f0in[b * NFRAMES + n];
    const float F_MIN = 72000.0f / 2045.0f;   // 3*fs/(L-3)
    if (f0 <= F_MIN) f0 = 500.0f;

    // ---- frame extraction + window ----
    float fr[8], wn[8];
    float hwl = rintf(36000.0f / f0);         // round(1.5*fs/f0), half-to-even
    float w2 = 0.0f;
#pragma unroll
    for (int c = 0; c < 8; ++c) {
        int l = tid + (c << 8);
        float relf = (float)(l - HALFN);
        int idx = n * FPER + l - HALFN;
        idx = max(0, min(TLEN - 1, idx));
        fr[c] = x[b * TLEN + idx];
        float w = 0.0f;
        if (fabsf(relf) <= hwl) {
            float arg = 3.14159265358979323846f * relf / 36000.0f * f0;
            w = 0.5f * cosf(arg) + 0.5f;
        }
        wn[c] = w;
        w2 += w * w;
    }
    w2 = blockReduceSum(w2, s_red, tid);
    float wscale = 1.0f / sqrtf(w2);
    float sw = 0.0f, swav = 0.0f;
#pragma unroll
    for (int c = 0; c < 8; ++c) {
        wn[c] *= wscale;          // normalized window
        fr[c] *= wn[c];           // wav = frames*win  (EPS_SAFE noise negligible)
        sw += wn[c]; swav += fr[c];
    }
    sw   = blockReduceSum(sw,   s_red, tid);
    swav = blockReduceSum(swav, s_red, tid);
    float dc = swav / sw;
    // load FFT1 input bit-reversed
#pragma unroll
    for (int c = 0; c < 8; ++c) {
        int l = tid + (c << 8);
        int r = __brev((unsigned)l) >> 21;
        s_re[r] = fr[c] - wn[c] * dc;
        s_im[r] = 0.0f;
    }
    __syncthreads();
    fft2048(s_re, s_im, s_twc, s_tws, tid);

    // ---- power spectrum ----
    for (int k = tid; k < K1; k += 256) {
        float a = s_re[k], bb = s_im[k];
        s_P[k] = a * a + bb * bb;
    }
    __syncthreads();

    // ---- sub-f0 replacement (k <= floor(rate), rate <= ~34) ----
    float rate = f0 * 2048.0f / 24000.0f;
    int kmax = (int)floorf(rate);
    float repl = 0.0f;
    if (tid <= kmax) {
        float m = rate - (float)tid;
        int lo = (int)floorf(m);
        lo = max(0, min(K1 - 2, lo));
        float frac = m - (float)lo;
        repl = s_P[lo] * (1.0f - frac) + s_P[lo + 1] * frac;
    }
    __syncthreads();
    if (tid <= kmax) s_P[tid] += repl;
    __syncthreads();

    // ---- reflected cumsum (inclusive scan over 1097 elements) ----
    float loc[5];
    float run = 0.0f;
    int base = tid * 5;
#pragma unroll
    for (int c = 0; c < 5; ++c) {
        int j = base + c;
        float v = 0.0f;
        if (j < MTOT) {
            int i = j - KPAD;
            int a = abs(i);
            if (a > HALFN) a = NFFT - a;
            v = s_P[a] * (24000.0f / 2048.0f);
        }
        run += v;
        loc[c] = run;
    }
    s_scan[tid] = run;
    __syncthreads();
    for (int off = 1; off < 256; off <<= 1) {
        float u = s_scan[tid];
        float w = (tid >= off) ? s_scan[tid - off] : 0.0f;
        __syncthreads();
        s_scan[tid] = u + w;
        __syncthreads();
    }
    float prefix = (tid > 0) ? s_scan[tid - 1] : 0.0f;
#pragma unroll
    for (int c = 0; c < 5; ++c) {
        int j = base + c;
        if (j < MTOT) s_C[j] = prefix + loc[c];
    }
    __syncthreads();

    // ---- rectangular smoothing + log (EPS_F32 noise negligible post-smoothing) ----
    float width = f0 * (2.0f / 3.0f);
    float wbins = width * 2048.0f / 24000.0f;
    for (int k = tid; k < K1; k += 256) {
        float pos_lo = (float)k - 0.5f * wbins + (KPAD - 0.5f);
        float pos_hi = pos_lo + wbins;
        int llo = (int)floorf(pos_lo); llo = max(0, min(MTOT - 2, llo));
        float flo = pos_lo - (float)llo;
        float clo = s_C[llo] + (s_C[llo + 1] - s_C[llo]) * flo;
        int lhi = (int)floorf(pos_hi); lhi = max(0, min(MTOT - 2, lhi));
        float fhi = pos_hi - (float)lhi;
        float chi = s_C[lhi] + (s_C[lhi + 1] - s_C[lhi]) * fhi;
        s_P[k] = logf((chi - clo) / width);
    }
    __syncthreads();

    // ---- FFT2: cep = irfft(logP) via FFT of even (hermitian) extension ----
#pragma unroll
    for (int c = 0; c < 8; ++c) {
        int i = tid + (c << 8);
        int r = __brev((unsigned)i) >> 21;
        int src = (r <= HALFN) ? r : (NFFT - r);
        s_re[i] = s_P[src];
        s_im[i] = 0.0f;
    }
    __syncthreads();
    fft2048(s_re, s_im, s_twc, s_tws, tid);

    // ---- lifter: cep * sinc(f0*q) * (1.3 - 0.3*cos(2*pi*f0*q)) ----
    for (int nn = tid; nn < K1; nn += 256) {
        float cep = s_re[nn] * (1.0f / 2048.0f);
        float z = f0 * ((float)nn * (1.0f / 24000.0f));
        float sl = 1.0f;
        if (nn != 0) {
            float pz = 3.14159265358979323846f * z;
            sl = sinf(pz) / pz;
        }
        float cl = 1.3f - 0.3f * cosf(6.283185307179586f * z);
        s_P[nn] = cep * sl * cl;
    }
    __syncthreads();

    // ---- FFT3: hfft(lift) via FFT of even extension ----
#pragma unroll
    for (int c = 0; c < 8; ++c) {
        int i = tid + (c << 8);
        int r = __brev((unsigned)i) >> 21;
        int src = (r <= HALFN) ? r : (NFFT - r);
        s_re[i] = s_P[src];
        s_im[i] = 0.0f;
    }
    __syncthreads();
    fft2048(s_re, s_im, s_twc, s_tws, tid);

    float* orow = out + (size_t)(b * NFRAMES + n) * K1;
    for (int m = tid; m < K1; m += 256) orow[m] = s_re[m];
}

extern "C" void kernel_launch(void* const* d_in, const int* in_sizes, int n_in,
                              void* d_out, int out_size, void* d_ws, size_t ws_size,
                              hipStream_t stream) {
    (void)in_sizes; (void)n_in; (void)d_ws; (void)ws_size; (void)out_size;
    const float* x  = (const float*)d_in[0];
    const float* f0 = (const float*)d_in[1];
    float* out = (float*)d_out;
    dim3 grid(NFRAMES, BATCH);
    hipLaunchKernelGGL(cheaptrick_kernel, grid, dim3(256), 0, stream, x, f0, out);
}

// Round 2
// 254.495 us; speedup vs baseline: 1.7636x; 1.7636x over previous
//
#include <hip/hip_runtime.h>
#include <math.h>

#define NFFT   2048
#define HALFN  1024
#define K1     1025
#define KPAD   36
#define MTOT   1097   // K1 + 2*KPAD
#define NFRAMES 1001
#define TLEN   120000
#define BATCH  8
#define FPER   120

// LDS swizzle for s_re/s_im: spreads brev/stride-8 patterns across banks.
#define A(i) ((i) + ((i) >> 3))      // max index 2047 -> 2302; arrays sized 2304
#define PIF 3.14159265358979323846f

__device__ __forceinline__ int brev11(int v) {
    return (int)(__brev((unsigned)v) >> 21);
}

// ---------------- fused radix-4 DIF stage (spans H and H/2) ----------------
// Natural-order input FFT; after all stages output at position p is X[brev11(p)].
template<int H>
__device__ __forceinline__ void dif_fused(float* re, float* im, int tid) {
#pragma unroll
    for (int q = 0; q < 2; ++q) {
        int u  = tid + (q << 8);                  // butterfly id in [0,512)
        int r  = u & (H / 2 - 1);
        int i0 = (u / (H / 2)) * (2 * H) + r;
        int ia = A(i0), ib = A(i0 + H / 2), ic = A(i0 + H), id = A(i0 + 3 * H / 2);
        float ar = re[ia], ai = im[ia];
        float br = re[ib], bi = im[ib];
        float cr = re[ic], ci = im[ic];
        float dr = re[id], di = im[id];
        float w1i, w1r;
        __sincosf(-PIF * (float)r / (float)H, &w1i, &w1r);   // w1 = W_{2H}^r
        // stage span H:
        float a1r = ar + cr, a1i = ai + ci;
        float t0r = ar - cr, t0i = ai - ci;
        float c1r = t0r * w1r - t0i * w1i, c1i = t0r * w1i + t0i * w1r;     // (a-c)*w1
        float b1r = br + dr, b1i = bi + di;
        float t1r = br - dr, t1i = bi - di;
        // (b-d) * (-i*w1)
        float d1r = t1r * w1i + t1i * w1r, d1i = t1i * w1i - t1r * w1r;
        // stage span H/2, twiddle w2 = w1^2:
        float w2r = w1r * w1r - w1i * w1i, w2i = 2.0f * w1r * w1i;
        float Ar = a1r + b1r, Ai = a1i + b1i;
        float t2r = a1r - b1r, t2i = a1i - b1i;
        float Br = t2r * w2r - t2i * w2i, Bi = t2r * w2i + t2i * w2r;
        float Cr = c1r + d1r, Ci = c1i + d1i;
        float t3r = c1r - d1r, t3i = c1i - d1i;
        float Dr = t3r * w2r - t3i * w2i, Di = t3r * w2i + t3i * w2r;
        re[ia] = Ar; im[ia] = Ai;
        re[ib] = Br; im[ib] = Bi;
        re[ic] = Cr; im[ic] = Ci;
        re[id] = Dr; im[id] = Di;
    }
    __syncthreads();
}

__device__ __forceinline__ void dif_last(float* re, float* im, int tid) {
#pragma unroll
    for (int c = 0; c < 4; ++c) {
        int p = tid + (c << 8);
        int a0 = A(2 * p), a1 = A(2 * p + 1);
        float ur = re[a0], ui = im[a0];
        float vr = re[a1], vi = im[a1];
        re[a0] = ur + vr; im[a0] = ui + vi;
        re[a1] = ur - vr; im[a1] = ui - vi;
    }
    __syncthreads();
}

__device__ __forceinline__ void dif_fft(float* re, float* im, int tid) {
    dif_fused<1024>(re, im, tid);
    dif_fused<256>(re, im, tid);
    dif_fused<64>(re, im, tid);
    dif_fused<16>(re, im, tid);
    dif_fused<4>(re, im, tid);
    dif_last(re, im, tid);
}

// ---------------- fused radix-4 DIT stage (spans H and 2H) ----------------
// Bit-reversed input (position p holds x[brev11(p)]); natural-order output.
template<int H>
__device__ __forceinline__ void dit_fused(float* re, float* im, int tid) {
#pragma unroll
    for (int q = 0; q < 2; ++q) {
        int u  = tid + (q << 8);
        int r  = u & (H - 1);
        int i0 = (u / H) * (4 * H) + r;
        int ia = A(i0), ib = A(i0 + H), ic = A(i0 + 2 * H), id = A(i0 + 3 * H);
        float ar = re[ia], ai = im[ia];
        float br = re[ib], bi = im[ib];
        float cr = re[ic], ci = im[ic];
        float dr = re[id], di = im[id];
        float w2i, w2r;
        __sincosf(-PIF * (float)r / (float)(2 * H), &w2i, &w2r);  // w2 = W_{4H}^r
        float w1r = w2r * w2r - w2i * w2i, w1i = 2.0f * w2r * w2i; // w1 = W_{2H}^r
        // stage span H:
        float tbr = br * w1r - bi * w1i, tbi = br * w1i + bi * w1r;
        float a1r = ar + tbr, a1i = ai + tbi;
        float b1r = ar - tbr, b1i = ai - tbi;
        float tdr = dr * w1r - di * w1i, tdi = dr * w1i + di * w1r;
        float c1r = cr + tdr, c1i = ci + tdi;
        float d1r = cr - tdr, d1i = ci - tdi;
        // stage span 2H:
        float tcr = c1r * w2r - c1i * w2i, tci = c1r * w2i + c1i * w2r;
        float Ar = a1r + tcr, Ai = a1i + tci;
        float Cr = a1r - tcr, Ci = a1i - tci;
        // w3 = -i*w2 ; t2 = d1*w3
        float t2r = d1r * w2i + d1i * w2r, t2i = d1i * w2i - d1r * w2r;
        float Br = b1r + t2r, Bi = b1i + t2i;
        float Dr = b1r - t2r, Di = b1i - t2i;
        re[ia] = Ar; im[ia] = Ai;
        re[ib] = Br; im[ib] = Bi;
        re[ic] = Cr; im[ic] = Ci;
        re[id] = Dr; im[id] = Di;
    }
    __syncthreads();
}

__device__ __forceinline__ void dit_last(float* re, float* im, int tid) {
#pragma unroll
    for (int c = 0; c < 4; ++c) {
        int p = tid + (c << 8);                    // pairs (p, p+1024)
        int a0 = A(p), a1 = A(p + 1024);
        float ur = re[a0], ui = im[a0];
        float vr = re[a1], vi = im[a1];
        float sn, cs;
        __sincosf(-PIF * (float)p * (1.0f / 1024.0f), &sn, &cs); // W_2048^p
        float tr = vr * cs - vi * sn, ti = vr * sn + vi * cs;
        re[a0] = ur + tr; im[a0] = ui + ti;
        re[a1] = ur - tr; im[a1] = ui - ti;
    }
    __syncthreads();
}

__device__ __forceinline__ void dit_fft(float* re, float* im, int tid) {
    dit_fused<1>(re, im, tid);
    dit_fused<4>(re, im, tid);
    dit_fused<16>(re, im, tid);
    dit_fused<64>(re, im, tid);
    dit_fused<256>(re, im, tid);
    dit_last(re, im, tid);
}

__global__ __launch_bounds__(256, 5)
void cheaptrick_kernel(const float* __restrict__ x,
                       const float* __restrict__ f0in,
                       float* __restrict__ out) {
    __shared__ float s_re[2304];
    __shared__ float s_im[2304];
    __shared__ float s_P[1026];
    __shared__ float s_C[MTOT];
    __shared__ float s_scan[16];

    const int tid  = threadIdx.x;
    const int lane = tid & 63;
    const int wid  = tid >> 6;
    const int n    = blockIdx.x;
    const int b    = blockIdx.y;

    float f0 = f0in[b * NFRAMES + n];
    const float F_MIN = 72000.0f / 2045.0f;
    if (f0 <= F_MIN) f0 = 500.0f;

    // ---- frame extraction + raw window; fused 3-sum reduction ----
    float fr[8], wn[8];
    float hwl = rintf(36000.0f / f0);
    float s_w2 = 0.0f, s_w = 0.0f, s_fw = 0.0f;
#pragma unroll
    for (int c = 0; c < 8; ++c) {
        int l = tid + (c << 8);
        float relf = (float)(l - HALFN);
        int idx = n * FPER + l - HALFN;
        idx = max(0, min(TLEN - 1, idx));
        fr[c] = x[b * TLEN + idx];
        float w = 0.0f;
        if (fabsf(relf) <= hwl) {
            w = 0.5f * cosf(PIF * relf / 36000.0f * f0) + 0.5f;
        }
        wn[c] = w;
        s_w2 += w * w;
        s_w  += w;
        s_fw += fr[c] * w;
    }
#pragma unroll
    for (int off = 32; off > 0; off >>= 1) {
        s_w2 += __shfl_down(s_w2, off, 64);
        s_w  += __shfl_down(s_w,  off, 64);
        s_fw += __shfl_down(s_fw, off, 64);
    }
    if (lane == 0) {
        s_scan[wid]     = s_w2;
        s_scan[4 + wid] = s_w;
        s_scan[8 + wid] = s_fw;
    }
    __syncthreads();
    float w2sum = s_scan[0] + s_scan[1] + s_scan[2] + s_scan[3];
    float wsum  = s_scan[4] + s_scan[5] + s_scan[6] + s_scan[7];
    float fwsum = s_scan[8] + s_scan[9] + s_scan[10] + s_scan[11];
    float wscale = 1.0f / sqrtf(w2sum);
    float dc = fwsum / wsum;

    // ---- FFT1 input (natural order, no scatter) ----
#pragma unroll
    for (int c = 0; c < 8; ++c) {
        int l = tid + (c << 8);
        s_re[A(l)] = wscale * wn[c] * (fr[c] - dc);
        s_im[A(l)] = 0.0f;
    }
    __syncthreads();
    dif_fft(s_re, s_im, tid);          // output at p = brev(k)

    // ---- power spectrum, gathered to natural order ----
    for (int k = tid; k < K1; k += 256) {
        int p = brev11(k);
        float xr = s_re[A(p)], xi = s_im[A(p)];
        s_P[k] = xr * xr + xi * xi;
    }
    __syncthreads();

    // ---- sub-f0 replacement ----
    float rate = f0 * (2048.0f / 24000.0f);
    int kmax = (int)floorf(rate);
    float repl = 0.0f;
    if (tid <= kmax) {
        float m = rate - (float)tid;
        int lo = (int)floorf(m);
        lo = max(0, min(K1 - 2, lo));
        float frac = m - (float)lo;
        repl = s_P[lo] * (1.0f - frac) + s_P[lo + 1] * frac;
    }
    __syncthreads();
    if (tid <= kmax) s_P[tid] += repl;
    __syncthreads();

    // ---- reflected cumsum: serial-5 + wave shuffle scan ----
    float loc[5];
    float run = 0.0f;
    int basej = tid * 5;
#pragma unroll
    for (int c = 0; c < 5; ++c) {
        int j = basej + c;
        float v = 0.0f;
        if (j < MTOT) {
            int a = abs(j - KPAD);
            if (a > HALFN) a = NFFT - a;
            v = s_P[a] * (24000.0f / 2048.0f);
        }
        run += v;
        loc[c] = run;
    }
    float v = run;
#pragma unroll
    for (int off = 1; off < 64; off <<= 1) {
        float o = __shfl_up(v, off, 64);
        if (lane >= off) v += o;
    }
    if (lane == 63) s_scan[wid] = v;
    __syncthreads();
    float wbase = 0.0f;
#pragma unroll
    for (int w = 0; w < 4; ++w) wbase += (w < wid) ? s_scan[w] : 0.0f;
    float prefix = wbase + v - run;    // exclusive prefix for this thread
#pragma unroll
    for (int c = 0; c < 5; ++c) {
        int j = basej + c;
        if (j < MTOT) s_C[j] = prefix + loc[c];
    }
    __syncthreads();

    // ---- rectangular smoothing + log ----
    float width = f0 * (2.0f / 3.0f);
    float wbins = width * (2048.0f / 24000.0f);
    for (int k = tid; k < K1; k += 256) {
        float pos_lo = (float)k - 0.5f * wbins + ((float)KPAD - 0.5f);
        float pos_hi = pos_lo + wbins;
        int llo = (int)floorf(pos_lo); llo = max(0, min(MTOT - 2, llo));
        float flo = pos_lo - (float)llo;
        float clo = s_C[llo] + (s_C[llo + 1] - s_C[llo]) * flo;
        int lhi = (int)floorf(pos_hi); lhi = max(0, min(MTOT - 2, lhi));
        float fhi = pos_hi - (float)lhi;
        float chi = s_C[lhi] + (s_C[lhi + 1] - s_C[lhi]) * fhi;
        s_P[k] = logf((chi - clo) / width);
    }
    __syncthreads();

    // ---- FFT2: even extension of logP, natural order in ----
#pragma unroll
    for (int c = 0; c < 8; ++c) {
        int i = tid + (c << 8);
        int src = (i <= HALFN) ? i : (NFFT - i);
        s_re[A(i)] = s_P[src];
        s_im[A(i)] = 0.0f;
    }
    __syncthreads();
    dif_fft(s_re, s_im, tid);          // cep[n] at position brev(n)

    // ---- lifter in bit-reversed space; build FFT3 (DIT) input ----
    // pass 1: positions with n = brev(p) <= 1024 get cep*lif/2048
#pragma unroll
    for (int c = 0; c < 8; ++c) {
        int p = tid + (c << 8);
        int nn = brev11(p);
        if (nn <= HALFN) {
            float cep = s_re[A(p)] * (1.0f / 2048.0f);
            float z = f0 * ((float)nn * (1.0f / 24000.0f));
            float sl = 1.0f;
            if (nn != 0) {
                float pz = PIF * z;
                sl = sinf(pz) / pz;
            }
            float cl = 1.3f - 0.3f * cosf(2.0f * PIF * z);
            s_re[A(p)] = cep * sl * cl;
            s_im[A(p)] = 0.0f;
        }
    }
    __syncthreads();
    // pass 2: positions with n > 1024 mirror from n' = 2048-n (already lifted)
#pragma unroll
    for (int c = 0; c < 8; ++c) {
        int p = tid + (c << 8);
        int nn = brev11(p);
        if (nn > HALFN) {
            int q = brev11(NFFT - nn);
            s_re[A(p)] = s_re[A(q)];
            s_im[A(p)] = 0.0f;
        }
    }
    __syncthreads();
    dit_fft(s_re, s_im, tid);          // natural-order output

    float* orow = out + (size_t)(b * NFRAMES + n) * K1;
    for (int m = tid; m < K1; m += 256) orow[m] = s_re[A(m)];
}

extern "C" void kernel_launch(void* const* d_in, const int* in_sizes, int n_in,
                              void* d_out, int out_size, void* d_ws, size_t ws_size,
                              hipStream_t stream) {
    (void)in_sizes; (void)n_in; (void)d_ws; (void)ws_size; (void)out_size;
    const float* x  = (const float*)d_in[0];
    const float* f0 = (const float*)d_in[1];
    float* out = (float*)d_out;
    dim3 grid(NFRAMES, BATCH);
    hipLaunchKernelGGL(cheaptrick_kernel, grid, dim3(256), 0, stream, x, f0, out);
}

// Round 3
// 243.248 us; speedup vs baseline: 1.8451x; 1.0462x over previous
//
#include <hip/hip_runtime.h>
#include <math.h>

#define NFFT   2048
#define HALFN  1024
#define K1     1025
#define KPAD   36
#define MTOT   1097   // K1 + 2*KPAD
#define NFRAMES 1001
#define TLEN   120000
#define BATCH  8
#define FPER   120

// LDS swizzle on complex-element index (spreads brev/stride-8 patterns).
#define A(i) ((i) + ((i) >> 3))      // max 2047 -> 2302; array sized 2304
#define PIF 3.14159265358979323846f

typedef float2 cpx;
__device__ __forceinline__ cpx cmul(cpx a, cpx b) {
    return make_float2(a.x * b.x - a.y * b.y, a.x * b.y + a.y * b.x);
}
__device__ __forceinline__ cpx cadd(cpx a, cpx b) { return make_float2(a.x + b.x, a.y + b.y); }
__device__ __forceinline__ cpx csub(cpx a, cpx b) { return make_float2(a.x - b.x, a.y - b.y); }

__device__ __forceinline__ int brev11(int v) {
    return (int)(__brev((unsigned)v) >> 21);
}

// ---------------- fused radix-4 DIF stage (spans H and H/2) ----------------
// Natural-order input FFT; after all stages output at position p is X[brev11(p)].
template<int H>
__device__ __forceinline__ void dif_fused(cpx* c, int tid) {
#pragma unroll
    for (int q = 0; q < 2; ++q) {
        int u  = tid + (q << 8);                  // butterfly id in [0,512)
        int r  = u & (H / 2 - 1);
        int i0 = (u / (H / 2)) * (2 * H) + r;
        int ia = A(i0), ib = A(i0 + H / 2), ic = A(i0 + H), id = A(i0 + 3 * H / 2);
        cpx a = c[ia], b = c[ib], cc = c[ic], d = c[id];
        float w1r, w1i;
        __sincosf(-PIF * (float)r / (float)H, &w1i, &w1r);   // w1 = W_{2H}^r
        cpx w1  = make_float2(w1r, w1i);
        cpx w1n = make_float2(w1i, -w1r);                    // -i*w1
        cpx w2  = make_float2(w1r * w1r - w1i * w1i, 2.0f * w1r * w1i);
        // stage span H:
        cpx a1 = cadd(a, cc);
        cpx c1 = cmul(csub(a, cc), w1);
        cpx b1 = cadd(b, d);
        cpx d1 = cmul(csub(b, d), w1n);
        // stage span H/2:
        c[ia] = cadd(a1, b1);
        c[ib] = cmul(csub(a1, b1), w2);
        c[ic] = cadd(c1, d1);
        c[id] = cmul(csub(c1, d1), w2);
    }
    __syncthreads();
}

__device__ __forceinline__ void dif_last(cpx* c, int tid) {
#pragma unroll
    for (int p4 = 0; p4 < 4; ++p4) {
        int p = tid + (p4 << 8);
        int a0 = A(2 * p), a1 = A(2 * p + 1);
        cpx u = c[a0], v = c[a1];
        c[a0] = cadd(u, v);
        c[a1] = csub(u, v);
    }
    __syncthreads();
}

__device__ __forceinline__ void dif_fft(cpx* c, int tid) {
    dif_fused<1024>(c, tid);
    dif_fused<256>(c, tid);
    dif_fused<64>(c, tid);
    dif_fused<16>(c, tid);
    dif_fused<4>(c, tid);
    dif_last(c, tid);
}

// ---------------- fused radix-4 DIT stage (spans H and 2H) ----------------
// Bit-reversed input (position p holds x[brev11(p)]); natural-order output.
template<int H>
__device__ __forceinline__ void dit_fused(cpx* c, int tid) {
#pragma unroll
    for (int q = 0; q < 2; ++q) {
        int u  = tid + (q << 8);
        int r  = u & (H - 1);
        int i0 = (u / H) * (4 * H) + r;
        int ia = A(i0), ib = A(i0 + H), ic = A(i0 + 2 * H), id = A(i0 + 3 * H);
        cpx a = c[ia], b = c[ib], cc = c[ic], d = c[id];
        float w2r, w2i;
        __sincosf(-PIF * (float)r / (float)(2 * H), &w2i, &w2r);  // w2 = W_{4H}^r
        cpx w2  = make_float2(w2r, w2i);
        cpx w1  = make_float2(w2r * w2r - w2i * w2i, 2.0f * w2r * w2i); // w1 = W_{2H}^r
        cpx w3  = make_float2(w2i, -w2r);                              // -i*w2
        // stage span H:
        cpx tb = cmul(b, w1);
        cpx a1 = cadd(a, tb), b1 = csub(a, tb);
        cpx td = cmul(d, w1);
        cpx c1 = cadd(cc, td), d1 = csub(cc, td);
        // stage span 2H:
        cpx tc = cmul(c1, w2);
        cpx t2 = cmul(d1, w3);
        c[ia] = cadd(a1, tc);
        c[ib] = cadd(b1, t2);
        c[ic] = csub(a1, tc);
        c[id] = csub(b1, t2);
    }
    __syncthreads();
}

__device__ __forceinline__ void dit_last(cpx* c, int tid) {
#pragma unroll
    for (int p4 = 0; p4 < 4; ++p4) {
        int p = tid + (p4 << 8);                    // pairs (p, p+1024)
        int a0 = A(p), a1 = A(p + 1024);
        cpx u = c[a0], v = c[a1];
        float sn, cs;
        __sincosf(-PIF * (float)p * (1.0f / 1024.0f), &sn, &cs); // W_2048^p
        cpx t = cmul(v, make_float2(cs, sn));
        c[a0] = cadd(u, t);
        c[a1] = csub(u, t);
    }
    __syncthreads();
}

__device__ __forceinline__ void dit_fft(cpx* c, int tid) {
    dit_fused<1>(c, tid);
    dit_fused<4>(c, tid);
    dit_fused<16>(c, tid);
    dit_fused<64>(c, tid);
    dit_fused<256>(c, tid);
    dit_last(c, tid);
}

__global__ __launch_bounds__(256, 4)
void cheaptrick_kernel(const float* __restrict__ x,
                       const float* __restrict__ f0in,
                       float* __restrict__ out) {
    __shared__ cpx   s_c[2304];
    __shared__ float s_P[1026];
    __shared__ float s_C[MTOT];
    __shared__ float s_scan[16];

    const int tid  = threadIdx.x;
    const int lane = tid & 63;
    const int wid  = tid >> 6;
    const int n    = blockIdx.x;
    const int b    = blockIdx.y;

    float f0 = f0in[b * NFRAMES + n];
    const float F_MIN = 72000.0f / 2045.0f;
    if (f0 <= F_MIN) f0 = 500.0f;

    // ---- frame extraction + raw window; fused 3-sum reduction ----
    float fr[8], wn[8];
    float hwl = rintf(36000.0f / f0);
    float s_w2 = 0.0f, s_w = 0.0f, s_fw = 0.0f;
#pragma unroll
    for (int c = 0; c < 8; ++c) {
        int l = tid + (c << 8);
        float relf = (float)(l - HALFN);
        int idx = n * FPER + l - HALFN;
        idx = max(0, min(TLEN - 1, idx));
        fr[c] = x[b * TLEN + idx];
        float w = 0.0f;
        if (fabsf(relf) <= hwl) {
            w = 0.5f * cosf(PIF * relf / 36000.0f * f0) + 0.5f;
        }
        wn[c] = w;
        s_w2 += w * w;
        s_w  += w;
        s_fw += fr[c] * w;
    }
#pragma unroll
    for (int off = 32; off > 0; off >>= 1) {
        s_w2 += __shfl_down(s_w2, off, 64);
        s_w  += __shfl_down(s_w,  off, 64);
        s_fw += __shfl_down(s_fw, off, 64);
    }
    if (lane == 0) {
        s_scan[wid]     = s_w2;
        s_scan[4 + wid] = s_w;
        s_scan[8 + wid] = s_fw;
    }
    __syncthreads();
    float w2sum = s_scan[0] + s_scan[1] + s_scan[2] + s_scan[3];
    float wsum  = s_scan[4] + s_scan[5] + s_scan[6] + s_scan[7];
    float fwsum = s_scan[8] + s_scan[9] + s_scan[10] + s_scan[11];
    float wscale = 1.0f / sqrtf(w2sum);
    float dc = fwsum / wsum;

    // ---- FFT1 input (natural order, no scatter) ----
#pragma unroll
    for (int c = 0; c < 8; ++c) {
        int l = tid + (c << 8);
        s_c[A(l)] = make_float2(wscale * wn[c] * (fr[c] - dc), 0.0f);
    }
    __syncthreads();
    dif_fft(s_c, tid);                 // output at p = brev(k)

    // ---- power spectrum, gathered to natural order ----
    for (int k = tid; k < K1; k += 256) {
        cpx v = s_c[A(brev11(k))];
        s_P[k] = v.x * v.x + v.y * v.y;
    }
    __syncthreads();

    // ---- sub-f0 replacement ----
    float rate = f0 * (2048.0f / 24000.0f);
    int kmax = (int)floorf(rate);
    float repl = 0.0f;
    if (tid <= kmax) {
        float m = rate - (float)tid;
        int lo = (int)floorf(m);
        lo = max(0, min(K1 - 2, lo));
        float frac = m - (float)lo;
        repl = s_P[lo] * (1.0f - frac) + s_P[lo + 1] * frac;
    }
    __syncthreads();
    if (tid <= kmax) s_P[tid] += repl;
    __syncthreads();

    // ---- reflected cumsum: serial-5 + wave shuffle scan ----
    float loc[5];
    float run = 0.0f;
    int basej = tid * 5;
#pragma unroll
    for (int c = 0; c < 5; ++c) {
        int j = basej + c;
        float v = 0.0f;
        if (j < MTOT) {
            int a = abs(j - KPAD);
            if (a > HALFN) a = NFFT - a;
            v = s_P[a] * (24000.0f / 2048.0f);
        }
        run += v;
        loc[c] = run;
    }
    float v = run;
#pragma unroll
    for (int off = 1; off < 64; off <<= 1) {
        float o = __shfl_up(v, off, 64);
        if (lane >= off) v += o;
    }
    if (lane == 63) s_scan[wid] = v;
    __syncthreads();
    float wbase = 0.0f;
#pragma unroll
    for (int w = 0; w < 4; ++w) wbase += (w < wid) ? s_scan[w] : 0.0f;
    float prefix = wbase + v - run;    // exclusive prefix for this thread
#pragma unroll
    for (int c = 0; c < 5; ++c) {
        int j = basej + c;
        if (j < MTOT) s_C[j] = prefix + loc[c];
    }
    __syncthreads();

    // ---- rectangular smoothing + log ----
    float width = f0 * (2.0f / 3.0f);
    float wbins = width * (2048.0f / 24000.0f);
    for (int k = tid; k < K1; k += 256) {
        float pos_lo = (float)k - 0.5f * wbins + ((float)KPAD - 0.5f);
        float pos_hi = pos_lo + wbins;
        int llo = (int)floorf(pos_lo); llo = max(0, min(MTOT - 2, llo));
        float flo = pos_lo - (float)llo;
        float clo = s_C[llo] + (s_C[llo + 1] - s_C[llo]) * flo;
        int lhi = (int)floorf(pos_hi); lhi = max(0, min(MTOT - 2, lhi));
        float fhi = pos_hi - (float)lhi;
        float chi = s_C[lhi] + (s_C[lhi + 1] - s_C[lhi]) * fhi;
        s_P[k] = logf((chi - clo) / width);
    }
    __syncthreads();

    // ---- FFT2: even extension of logP, natural order in ----
#pragma unroll
    for (int c = 0; c < 8; ++c) {
        int i = tid + (c << 8);
        int src = (i <= HALFN) ? i : (NFFT - i);
        s_c[A(i)] = make_float2(s_P[src], 0.0f);
    }
    __syncthreads();
    dif_fft(s_c, tid);                 // cep[n] at position brev(n)

    // ---- lifter in bit-reversed space; build FFT3 (DIT) input ----
#pragma unroll
    for (int c = 0; c < 8; ++c) {
        int p = tid + (c << 8);
        int nn = brev11(p);
        if (nn <= HALFN) {
            float cep = s_c[A(p)].x * (1.0f / 2048.0f);
            float z = f0 * ((float)nn * (1.0f / 24000.0f));
            float sl = 1.0f;
            if (nn != 0) {
                float pz = PIF * z;
                sl = sinf(pz) / pz;
            }
            float cl = 1.3f - 0.3f * cosf(2.0f * PIF * z);
            s_c[A(p)] = make_float2(cep * sl * cl, 0.0f);
        }
    }
    __syncthreads();
#pragma unroll
    for (int c = 0; c < 8; ++c) {
        int p = tid + (c << 8);
        int nn = brev11(p);
        if (nn > HALFN) {
            int q = brev11(NFFT - nn);
            s_c[A(p)] = make_float2(s_c[A(q)].x, 0.0f);
        }
    }
    __syncthreads();
    dit_fft(s_c, tid);                 // natural-order output

    float* orow = out + (size_t)(b * NFRAMES + n) * K1;
    for (int m = tid; m < K1; m += 256) orow[m] = s_c[A(m)].x;
}

extern "C" void kernel_launch(void* const* d_in, const int* in_sizes, int n_in,
                              void* d_out, int out_size, void* d_ws, size_t ws_size,
                              hipStream_t stream) {
    (void)in_sizes; (void)n_in; (void)d_ws; (void)ws_size; (void)out_size;
    const float* x  = (const float*)d_in[0];
    const float* f0 = (const float*)d_in[1];
    float* out = (float*)d_out;
    dim3 grid(NFRAMES, BATCH);
    hipLaunchKernelGGL(cheaptrick_kernel, grid, dim3(256), 0, stream, x, f0, out);
}

// Round 4
// 178.898 us; speedup vs baseline: 2.5088x; 1.3597x over previous
//
#include <hip/hip_runtime.h>
#include <math.h>

#define NFFT   2048
#define N1     1024
#define K1     1025
#define KPAD   36
#define MTOT   1097   // K1 + 2*KPAD
#define NFRAMES 1001
#define TLEN   120000
#define BATCH  8
#define FPER   120
#define PIF 3.14159265358979323846f

// LDS swizzle for 8B (float2) elements: bank-pair index = A(i) mod 16.
// Verified balanced (4 lanes per residue per wave) for all radix-4 stage
// strides and for the stride-16 brev gather in unpack.
#define A(i) ((i) + ((i) >> 4))      // max 1023 -> 1086; array sized 1088

typedef float2 cpx;
__device__ __forceinline__ cpx cmul(cpx a, cpx b) {
    return make_float2(a.x * b.x - a.y * b.y, a.x * b.y + a.y * b.x);
}
__device__ __forceinline__ cpx cadd(cpx a, cpx b) { return make_float2(a.x + b.x, a.y + b.y); }
__device__ __forceinline__ cpx csub(cpx a, cpx b) { return make_float2(a.x - b.x, a.y - b.y); }

__device__ __forceinline__ int brev10(int v) {
    return (int)(__brev((unsigned)v) >> 22);
}

// ---- fused radix-4 DIF stage (spans H and H/2) on 1024 points ----
// 256 butterflies, one per thread. Natural-order input; after the 5 stages
// position p holds X[brev10(p)].
template<int H>
__device__ __forceinline__ void dif_fused(cpx* c, int tid) {
    int r  = tid & (H / 2 - 1);
    int i0 = (tid / (H / 2)) * (2 * H) + r;
    int ia = A(i0), ib = A(i0 + H / 2), ic = A(i0 + H), id = A(i0 + 3 * H / 2);
    cpx a = c[ia], b = c[ib], cc = c[ic], d = c[id];
    float w1r, w1i;
    __sincosf(-PIF * (float)r / (float)H, &w1i, &w1r);   // w1 = W_{2H}^r
    cpx w1  = make_float2(w1r, w1i);
    cpx w1n = make_float2(w1i, -w1r);                    // -i*w1
    cpx w2  = make_float2(w1r * w1r - w1i * w1i, 2.0f * w1r * w1i);
    // stage span H:
    cpx a1 = cadd(a, cc);
    cpx c1 = cmul(csub(a, cc), w1);
    cpx b1 = cadd(b, d);
    cpx d1 = cmul(csub(b, d), w1n);
    // stage span H/2:
    c[ia] = cadd(a1, b1);
    c[ib] = cmul(csub(a1, b1), w2);
    c[ic] = cadd(c1, d1);
    c[id] = cmul(csub(c1, d1), w2);
    __syncthreads();
}

__device__ __forceinline__ void fft1024(cpx* c, int tid) {
    dif_fused<512>(c, tid);
    dif_fused<128>(c, tid);
    dif_fused<32>(c, tid);
    dif_fused<8>(c, tid);
    dif_fused<2>(c, tid);
}

// Unpack helper: given packed-FFT result Z (bit-reversed in s_c), produce
// X[k] = E + W_2048^k * O for the length-2048 transform of the interleaved
// real sequence. Returns full complex X.
__device__ __forceinline__ cpx unpack_k(const cpx* s_c, int k) {
    int kk = k & (N1 - 1);
    int mm = (N1 - kk) & (N1 - 1);
    cpx Zk = s_c[A(brev10(kk))];
    cpx Zm = s_c[A(brev10(mm))];
    float Ex = 0.5f * (Zk.x + Zm.x), Ey = 0.5f * (Zk.y - Zm.y);
    float Ox = 0.5f * (Zk.y + Zm.y), Oy = 0.5f * (Zm.x - Zk.x);
    float sw_, cw_;
    __sincosf(-PIF * (float)k * (1.0f / 1024.0f), &sw_, &cw_);  // W_2048^k
    return make_float2(Ex + cw_ * Ox - sw_ * Oy,
                       Ey + cw_ * Oy + sw_ * Ox);
}

__global__ __launch_bounds__(256, 6)
void cheaptrick_kernel(const float* __restrict__ x,
                       const float* __restrict__ f0in,
                       float* __restrict__ out) {
    __shared__ cpx   s_c[1088];
    __shared__ float s_P[1026];
    __shared__ float s_C[MTOT];
    __shared__ float s_scan[16];

    const int tid  = threadIdx.x;
    const int lane = tid & 63;
    const int wid  = tid >> 6;
    const int n    = blockIdx.x;
    const int b    = blockIdx.y;

    float f0 = f0in[b * NFRAMES + n];
    const float F_MIN = 72000.0f / 2045.0f;
    if (f0 <= F_MIN) f0 = 500.0f;

    // ---- frame extraction + raw window (thread-contiguous l = 8t+j) ----
    float fr[8], wn[8];
    float hwl = rintf(36000.0f / f0);
    float s_w2 = 0.0f, s_w = 0.0f, s_fw = 0.0f;
    int base_idx = n * FPER - N1 + 8 * tid;
#pragma unroll
    for (int j = 0; j < 8; ++j) {
        int l = 8 * tid + j;
        float relf = (float)(l - N1);
        int idx = max(0, min(TLEN - 1, base_idx + j));
        fr[j] = x[b * TLEN + idx];
        float w = 0.0f;
        if (fabsf(relf) <= hwl) {
            w = 0.5f * cosf(PIF * relf / 36000.0f * f0) + 0.5f;
        }
        wn[j] = w;
        s_w2 += w * w;
        s_w  += w;
        s_fw += fr[j] * w;
    }
#pragma unroll
    for (int off = 32; off > 0; off >>= 1) {
        s_w2 += __shfl_down(s_w2, off, 64);
        s_w  += __shfl_down(s_w,  off, 64);
        s_fw += __shfl_down(s_fw, off, 64);
    }
    if (lane == 0) {
        s_scan[wid]     = s_w2;
        s_scan[4 + wid] = s_w;
        s_scan[8 + wid] = s_fw;
    }
    __syncthreads();
    float w2sum = s_scan[0] + s_scan[1] + s_scan[2] + s_scan[3];
    float wsum  = s_scan[4] + s_scan[5] + s_scan[6] + s_scan[7];
    float fwsum = s_scan[8] + s_scan[9] + s_scan[10] + s_scan[11];
    float wscale = 1.0f / sqrtf(w2sum);
    float dc = fwsum / wsum;
    __syncthreads();          // s_scan reuse below

    // ---- FFT1 pack (register-local): z[m] = w[2m] + i*w[2m+1], m=4t+j ----
#pragma unroll
    for (int j = 0; j < 4; ++j) {
        float v0 = wscale * wn[2 * j]     * (fr[2 * j]     - dc);
        float v1 = wscale * wn[2 * j + 1] * (fr[2 * j + 1] - dc);
        s_c[A(4 * tid + j)] = make_float2(v0, v1);
    }
    __syncthreads();
    fft1024(s_c, tid);

    // ---- unpack + power spectrum ----
    for (int k = tid; k < K1; k += 256) {
        cpx X = unpack_k(s_c, k);
        s_P[k] = X.x * X.x + X.y * X.y;
    }
    __syncthreads();

    // ---- sub-f0 replacement ----
    float rate = f0 * (2048.0f / 24000.0f);
    int kmax = (int)floorf(rate);
    float repl = 0.0f;
    if (tid <= kmax) {
        float m = rate - (float)tid;
        int lo = (int)floorf(m);
        lo = max(0, min(K1 - 2, lo));
        float frac = m - (float)lo;
        repl = s_P[lo] * (1.0f - frac) + s_P[lo + 1] * frac;
    }
    __syncthreads();
    if (tid <= kmax) s_P[tid] += repl;
    __syncthreads();

    // ---- reflected cumsum: serial-5 + wave shuffle scan ----
    float loc[5];
    float run = 0.0f;
    int basej = tid * 5;
#pragma unroll
    for (int c = 0; c < 5; ++c) {
        int j = basej + c;
        float v = 0.0f;
        if (j < MTOT) {
            int a = abs(j - KPAD);
            if (a > N1) a = NFFT - a;
            v = s_P[a] * (24000.0f / 2048.0f);
        }
        run += v;
        loc[c] = run;
    }
    float v = run;
#pragma unroll
    for (int off = 1; off < 64; off <<= 1) {
        float o = __shfl_up(v, off, 64);
        if (lane >= off) v += o;
    }
    if (lane == 63) s_scan[wid] = v;
    __syncthreads();
    float wbase = 0.0f;
#pragma unroll
    for (int w = 0; w < 4; ++w) wbase += (w < wid) ? s_scan[w] : 0.0f;
    float prefix = wbase + v - run;
#pragma unroll
    for (int c = 0; c < 5; ++c) {
        int j = basej + c;
        if (j < MTOT) s_C[j] = prefix + loc[c];
    }
    __syncthreads();

    // ---- rectangular smoothing + log ----
    float width = f0 * (2.0f / 3.0f);
    float wbins = width * (2048.0f / 24000.0f);
    for (int k = tid; k < K1; k += 256) {
        float pos_lo = (float)k - 0.5f * wbins + ((float)KPAD - 0.5f);
        float pos_hi = pos_lo + wbins;
        int llo = (int)floorf(pos_lo); llo = max(0, min(MTOT - 2, llo));
        float flo = pos_lo - (float)llo;
        float clo = s_C[llo] + (s_C[llo + 1] - s_C[llo]) * flo;
        int lhi = (int)floorf(pos_hi); lhi = max(0, min(MTOT - 2, lhi));
        float fhi = pos_hi - (float)lhi;
        float chi = s_C[lhi] + (s_C[lhi + 1] - s_C[lhi]) * fhi;
        s_P[k] = logf((chi - clo) / width);
    }
    __syncthreads();

    // ---- FFT2: pack even extension of logP ----
#pragma unroll
    for (int c = 0; c < 4; ++c) {
        int m = tid + (c << 8);
        int j0 = 2 * m;
        int j1 = 2 * m + 1;
        float v0 = (j0 <= N1) ? s_P[j0] : s_P[NFFT - j0];
        float v1 = (j1 <= N1) ? s_P[j1] : s_P[NFFT - j1];
        s_c[A(m)] = make_float2(v0, v1);
    }
    __syncthreads();
    fft1024(s_c, tid);

    // ---- unpack + lifter -> s_P (lifted cepstrum, n=0..1024) ----
    for (int k = tid; k < K1; k += 256) {
        cpx X = unpack_k(s_c, k);
        float cep = X.x * (1.0f / 2048.0f);
        float z = f0 * ((float)k * (1.0f / 24000.0f));
        float sl = 1.0f;
        if (k != 0) {
            float pz = PIF * z;
            sl = sinf(pz) / pz;
        }
        float cl = 1.3f - 0.3f * cosf(2.0f * PIF * z);
        s_P[k] = cep * sl * cl;
    }
    __syncthreads();

    // ---- FFT3: pack even extension of lifted cepstrum ----
#pragma unroll
    for (int c = 0; c < 4; ++c) {
        int m = tid + (c << 8);
        int j0 = 2 * m;
        int j1 = 2 * m + 1;
        float v0 = (j0 <= N1) ? s_P[j0] : s_P[NFFT - j0];
        float v1 = (j1 <= N1) ? s_P[j1] : s_P[NFFT - j1];
        s_c[A(m)] = make_float2(v0, v1);
    }
    __syncthreads();
    fft1024(s_c, tid);

    // ---- unpack + store ----
    float* orow = out + (size_t)(b * NFRAMES + n) * K1;
    for (int k = tid; k < K1; k += 256) {
        cpx X = unpack_k(s_c, k);
        orow[k] = X.x;
    }
}

extern "C" void kernel_launch(void* const* d_in, const int* in_sizes, int n_in,
                              void* d_out, int out_size, void* d_ws, size_t ws_size,
                              hipStream_t stream) {
    (void)in_sizes; (void)n_in; (void)d_ws; (void)ws_size; (void)out_size;
    const float* x  = (const float*)d_in[0];
    const float* f0 = (const float*)d_in[1];
    float* out = (float*)d_out;
    dim3 grid(NFRAMES, BATCH);
    hipLaunchKernelGGL(cheaptrick_kernel, grid, dim3(256), 0, stream, x, f0, out);
}

// Round 5
// 162.789 us; speedup vs baseline: 2.7571x; 1.0990x over previous
//
#include <hip/hip_runtime.h>
#include <math.h>

#define NFFT   2048
#define N1     1024
#define K1     1025
#define KPAD   36
#define MTOT   1097   // K1 + 2*KPAD
#define NFRAMES 1001
#define TLEN   120000
#define BATCH  8
#define FPER   120
#define PIF 3.14159265358979323846f

// LDS swizzle for 8B (float2) elements; balanced for all radix-4 strides and
// the stride-16 brev gathers. Remaining SQ_LDS_BANK_CONFLICT (~1.4e7) is the
// intrinsic multi-cycle cost of 512B/wave b64 ops, not misalignment.
#define A(i) ((i) + ((i) >> 4))      // max 1023 -> 1086; array sized 1088

typedef float2 cpx;
__device__ __forceinline__ cpx cmul(cpx a, cpx b) {
    return make_float2(a.x * b.x - a.y * b.y, a.x * b.y + a.y * b.x);
}
__device__ __forceinline__ cpx cadd(cpx a, cpx b) { return make_float2(a.x + b.x, a.y + b.y); }
__device__ __forceinline__ cpx csub(cpx a, cpx b) { return make_float2(a.x - b.x, a.y - b.y); }

__device__ __forceinline__ int brev10(int v) {
    return (int)(__brev((unsigned)v) >> 22);
}

// ---- fused radix-4 DIF stage (spans H and H/2); w1 = W_{2H}^{tid&(H/2-1)} ----
template<int H>
__device__ __forceinline__ void dif_fused(cpx* c, int tid, cpx w1) {
    int r  = tid & (H / 2 - 1);
    int i0 = (tid / (H / 2)) * (2 * H) + r;
    int ia = A(i0), ib = A(i0 + H / 2), ic = A(i0 + H), id = A(i0 + 3 * H / 2);
    cpx a = c[ia], b = c[ib], cc = c[ic], d = c[id];
    cpx w1n = make_float2(w1.y, -w1.x);                       // -i*w1
    cpx w2  = make_float2(w1.x * w1.x - w1.y * w1.y, 2.0f * w1.x * w1.y);
    cpx a1 = cadd(a, cc);
    cpx c1 = cmul(csub(a, cc), w1);
    cpx b1 = cadd(b, d);
    cpx d1 = cmul(csub(b, d), w1n);
    c[ia] = cadd(a1, b1);
    c[ib] = cmul(csub(a1, b1), w2);
    c[ic] = cadd(c1, d1);
    c[id] = cmul(csub(c1, d1), w2);
    __syncthreads();
}

// last stage (H=2): twiddles are 1 and -i — no multiplies.
__device__ __forceinline__ void dif_last2(cpx* c, int tid) {
    int i0 = 4 * tid;
    int ia = A(i0), ib = A(i0 + 1), ic = A(i0 + 2), id = A(i0 + 3);
    cpx a = c[ia], b = c[ib], cc = c[ic], d = c[id];
    cpx a1 = cadd(a, cc);
    cpx c1 = csub(a, cc);
    cpx b1 = cadd(b, d);
    cpx bd = csub(b, d);
    cpx d1 = make_float2(bd.y, -bd.x);                        // -i*(b-d)
    c[ia] = cadd(a1, b1);
    c[ib] = csub(a1, b1);
    c[ic] = cadd(c1, d1);
    c[id] = csub(c1, d1);
    __syncthreads();
}

__device__ __forceinline__ void fft1024(cpx* c, int tid, const cpx* tw) {
    dif_fused<512>(c, tid, tw[0]);
    dif_fused<128>(c, tid, tw[1]);
    dif_fused<32>(c, tid, tw[2]);
    dif_fused<8>(c, tid, tw[3]);
    dif_last2(c, tid);
}

// Unpack: X[k] = E + w*O, w = W_2048^k (precomputed by caller).
__device__ __forceinline__ cpx unpack_k(const cpx* s_c, int k, cpx w) {
    int kk = k & (N1 - 1);
    int mm = (N1 - kk) & (N1 - 1);
    cpx Zk = s_c[A(brev10(kk))];
    cpx Zm = s_c[A(brev10(mm))];
    float Ex = 0.5f * (Zk.x + Zm.x), Ey = 0.5f * (Zk.y - Zm.y);
    float Ox = 0.5f * (Zk.y + Zm.y), Oy = 0.5f * (Zm.x - Zk.x);
    return make_float2(Ex + w.x * Ox - w.y * Oy,
                       Ey + w.x * Oy + w.y * Ox);
}

__global__ __launch_bounds__(256, 4)   // (256,4): 64 VGPR, spill-free (r3/r4 evidence)
void cheaptrick_kernel(const float* __restrict__ x,
                       const float* __restrict__ f0in,
                       float* __restrict__ out) {
    __shared__ cpx   s_c[1088];
    __shared__ float s_P[1026];
    __shared__ float s_C[MTOT];
    __shared__ float s_scan[16];

    const int tid  = threadIdx.x;
    const int lane = tid & 63;
    const int wid  = tid >> 6;
    const int n    = blockIdx.x;
    const int b    = blockIdx.y;

    float f0 = f0in[b * NFRAMES + n];
    const float F_MIN = 72000.0f / 2045.0f;
    if (f0 <= F_MIN) f0 = 500.0f;

    // ---- frame extraction + raw window (thread-contiguous l = 8t+j) ----
    float fr[8], wn[8];
    float hwl = rintf(36000.0f / f0);
    float s_w2 = 0.0f, s_w = 0.0f, s_fw = 0.0f;
    int base_idx = n * FPER - N1 + 8 * tid;
#pragma unroll
    for (int j = 0; j < 8; ++j) {
        int l = 8 * tid + j;
        float relf = (float)(l - N1);
        int idx = max(0, min(TLEN - 1, base_idx + j));
        fr[j] = x[b * TLEN + idx];
        float w = 0.0f;
        if (fabsf(relf) <= hwl) {
            w = 0.5f * __cosf(PIF * relf / 36000.0f * f0) + 0.5f;
        }
        wn[j] = w;
        s_w2 += w * w;
        s_w  += w;
        s_fw += fr[j] * w;
    }
#pragma unroll
    for (int off = 32; off > 0; off >>= 1) {
        s_w2 += __shfl_down(s_w2, off, 64);
        s_w  += __shfl_down(s_w,  off, 64);
        s_fw += __shfl_down(s_fw, off, 64);
    }
    if (lane == 0) {
        s_scan[wid]     = s_w2;
        s_scan[4 + wid] = s_w;
        s_scan[8 + wid] = s_fw;
    }
    __syncthreads();
    float w2sum = s_scan[0] + s_scan[1] + s_scan[2] + s_scan[3];
    float wsum  = s_scan[4] + s_scan[5] + s_scan[6] + s_scan[7];
    float fwsum = s_scan[8] + s_scan[9] + s_scan[10] + s_scan[11];
    float wscale = 1.0f / sqrtf(w2sum);
    float dc = fwsum / wsum;
    __syncthreads();          // s_scan reuse below

    // ---- FFT1 pack (register-local): z[m] = w[2m] + i*w[2m+1] ----
#pragma unroll
    for (int j = 0; j < 4; ++j) {
        float v0 = wscale * wn[2 * j]     * (fr[2 * j]     - dc);
        float v1 = wscale * wn[2 * j + 1] * (fr[2 * j + 1] - dc);
        s_c[A(4 * tid + j)] = make_float2(v0, v1);
    }

    // ---- twiddle caches (fr/wn now dead; computed once, reused by 3 FFTs) ----
    cpx tw[4], u2048;
    {
        float sn, cs;
        __sincosf(-PIF * (float)(tid & 255) * (1.0f / 512.0f), &sn, &cs);
        tw[0] = make_float2(cs, sn);
        __sincosf(-PIF * (float)(tid & 63) * (1.0f / 128.0f), &sn, &cs);
        tw[1] = make_float2(cs, sn);
        __sincosf(-PIF * (float)(tid & 15) * (1.0f / 32.0f), &sn, &cs);
        tw[2] = make_float2(cs, sn);
        __sincosf(-PIF * (float)(tid & 3) * (1.0f / 8.0f), &sn, &cs);
        tw[3] = make_float2(cs, sn);
        __sincosf(-PIF * (float)tid * (1.0f / 1024.0f), &sn, &cs);
        u2048 = make_float2(cs, sn);          // W_2048^tid
    }
    const float RH = 0.70710678118654752f;
    const cpx W8[5] = { make_float2(1.0f, 0.0f), make_float2(RH, -RH),
                        make_float2(0.0f, -1.0f), make_float2(-RH, -RH),
                        make_float2(-1.0f, 0.0f) };           // W_2048^(256c)

    __syncthreads();
    fft1024(s_c, tid, tw);

    // ---- unpack + power spectrum ----
#pragma unroll
    for (int c5 = 0; c5 < 5; ++c5) {
        int k = tid + (c5 << 8);
        if (k < K1) {
            cpx X = unpack_k(s_c, k, cmul(u2048, W8[c5]));
            s_P[k] = X.x * X.x + X.y * X.y;
        }
    }
    __syncthreads();

    // ---- sub-f0 replacement ----
    float rate = f0 * (2048.0f / 24000.0f);
    int kmax = (int)floorf(rate);
    float repl = 0.0f;
    if (tid <= kmax) {
        float m = rate - (float)tid;
        int lo = (int)floorf(m);
        lo = max(0, min(K1 - 2, lo));
        float frac = m - (float)lo;
        repl = s_P[lo] * (1.0f - frac) + s_P[lo + 1] * frac;
    }
    __syncthreads();
    if (tid <= kmax) s_P[tid] += repl;
    __syncthreads();

    // ---- reflected cumsum: serial-5 + wave shuffle scan ----
    float loc[5];
    float run = 0.0f;
    int basej = tid * 5;
#pragma unroll
    for (int c = 0; c < 5; ++c) {
        int j = basej + c;
        float v = 0.0f;
        if (j < MTOT) {
            int a = abs(j - KPAD);
            if (a > N1) a = NFFT - a;
            v = s_P[a] * (24000.0f / 2048.0f);
        }
        run += v;
        loc[c] = run;
    }
    float v = run;
#pragma unroll
    for (int off = 1; off < 64; off <<= 1) {
        float o = __shfl_up(v, off, 64);
        if (lane >= off) v += o;
    }
    if (lane == 63) s_scan[wid] = v;
    __syncthreads();
    float wbase = 0.0f;
#pragma unroll
    for (int w = 0; w < 4; ++w) wbase += (w < wid) ? s_scan[w] : 0.0f;
    float prefix = wbase + v - run;
#pragma unroll
    for (int c = 0; c < 5; ++c) {
        int j = basej + c;
        if (j < MTOT) s_C[j] = prefix + loc[c];
    }
    __syncthreads();

    // ---- rectangular smoothing + log ----
    float width = f0 * (2.0f / 3.0f);
    float wbins = width * (2048.0f / 24000.0f);
#pragma unroll
    for (int c5 = 0; c5 < 5; ++c5) {
        int k = tid + (c5 << 8);
        if (k < K1) {
            float pos_lo = (float)k - 0.5f * wbins + ((float)KPAD - 0.5f);
            float pos_hi = pos_lo + wbins;
            int llo = (int)floorf(pos_lo); llo = max(0, min(MTOT - 2, llo));
            float flo = pos_lo - (float)llo;
            float clo = s_C[llo] + (s_C[llo + 1] - s_C[llo]) * flo;
            int lhi = (int)floorf(pos_hi); lhi = max(0, min(MTOT - 2, lhi));
            float fhi = pos_hi - (float)lhi;
            float chi = s_C[lhi] + (s_C[lhi + 1] - s_C[lhi]) * fhi;
            s_P[k] = logf((chi - clo) / width);
        }
    }
    __syncthreads();

    // ---- FFT2: pack even extension of logP ----
#pragma unroll
    for (int c = 0; c < 4; ++c) {
        int m = tid + (c << 8);
        int j0 = 2 * m;
        int j1 = 2 * m + 1;
        float v0 = (j0 <= N1) ? s_P[j0] : s_P[NFFT - j0];
        float v1 = (j1 <= N1) ? s_P[j1] : s_P[NFFT - j1];
        s_c[A(m)] = make_float2(v0, v1);
    }
    __syncthreads();
    fft1024(s_c, tid, tw);

    // ---- unpack + lifter -> s_P ; cl via cos(2a)=1-2sin^2(a) ----
#pragma unroll
    for (int c5 = 0; c5 < 5; ++c5) {
        int k = tid + (c5 << 8);
        if (k < K1) {
            cpx X = unpack_k(s_c, k, cmul(u2048, W8[c5]));
            float cep = X.x * (1.0f / 2048.0f);
            float pz = PIF * f0 * ((float)k * (1.0f / 24000.0f));
            float s = __sinf(pz);
            float sl = (k != 0) ? (s / pz) : 1.0f;
            float cl = 1.0f + 0.6f * s * s;
            s_P[k] = cep * sl * cl;
        }
    }
    __syncthreads();

    // ---- FFT3: pack even extension of lifted cepstrum ----
#pragma unroll
    for (int c = 0; c < 4; ++c) {
        int m = tid + (c << 8);
        int j0 = 2 * m;
        int j1 = 2 * m + 1;
        float v0 = (j0 <= N1) ? s_P[j0] : s_P[NFFT - j0];
        float v1 = (j1 <= N1) ? s_P[j1] : s_P[NFFT - j1];
        s_c[A(m)] = make_float2(v0, v1);
    }
    __syncthreads();
    fft1024(s_c, tid, tw);

    // ---- unpack + store ----
    float* orow = out + (size_t)(b * NFRAMES + n) * K1;
#pragma unroll
    for (int c5 = 0; c5 < 5; ++c5) {
        int k = tid + (c5 << 8);
        if (k < K1) {
            cpx X = unpack_k(s_c, k, cmul(u2048, W8[c5]));
            orow[k] = X.x;
        }
    }
}

extern "C" void kernel_launch(void* const* d_in, const int* in_sizes, int n_in,
                              void* d_out, int out_size, void* d_ws, size_t ws_size,
                              hipStream_t stream) {
    (void)in_sizes; (void)n_in; (void)d_ws; (void)ws_size; (void)out_size;
    const float* x  = (const float*)d_in[0];
    const float* f0 = (const float*)d_in[1];
    float* out = (float*)d_out;
    dim3 grid(NFRAMES, BATCH);
    hipLaunchKernelGGL(cheaptrick_kernel, grid, dim3(256), 0, stream, x, f0, out);
}